// Round 2
// baseline (417.462 us; speedup 1.0000x reference)
//
#include <hip/hip_runtime.h>
#include <cstdint>
#include <cstddef>

#define BDIM 8192
#define DDIM 512

typedef __bf16 bf16x8 __attribute__((ext_vector_type(8)));
typedef float f32x4 __attribute__((ext_vector_type(4)));

__device__ inline unsigned short f32_to_bf16(float f) {
    unsigned int u = __float_as_uint(f);
    u += 0x7FFF + ((u >> 16) & 1);   // RNE
    return (unsigned short)(u >> 16);
}

// One WAVE per row (no LDS, no barriers). 256 threads = 4 rows/block.
__global__ __launch_bounds__(256) void normalize_kernel(
    const float* __restrict__ a, const float* __restrict__ b,
    unsigned short* __restrict__ an, unsigned short* __restrict__ bn)
{
    const int lane = threadIdx.x & 63;
    const int row = blockIdx.x * 4 + (threadIdx.x >> 6);
    const float* src;
    unsigned short* dst;
    if (row < BDIM) {
        src = a + (size_t)row * DDIM;
        dst = an + (size_t)row * DDIM;
    } else {
        src = b + (size_t)(row - BDIM) * DDIM;
        dst = bn + (size_t)(row - BDIM) * DDIM;
    }
    const float4* s4 = (const float4*)src;
    float4 v0 = s4[lane];
    float4 v1 = s4[lane + 64];
    float ss = v0.x * v0.x + v0.y * v0.y + v0.z * v0.z + v0.w * v0.w
             + v1.x * v1.x + v1.y * v1.y + v1.z * v1.z + v1.w * v1.w;
#pragma unroll
    for (int m = 1; m < 64; m <<= 1) ss += __shfl_xor(ss, m);
    float inv = 1.0f / fmaxf(sqrtf(ss), 1e-8f);
    ushort4 o0, o1;
    o0.x = f32_to_bf16(v0.x * inv); o0.y = f32_to_bf16(v0.y * inv);
    o0.z = f32_to_bf16(v0.z * inv); o0.w = f32_to_bf16(v0.w * inv);
    o1.x = f32_to_bf16(v1.x * inv); o1.y = f32_to_bf16(v1.y * inv);
    o1.z = f32_to_bf16(v1.z * inv); o1.w = f32_to_bf16(v1.w * inv);
    ushort4* d4 = (ushort4*)dst;
    d4[lane] = o0;
    d4[lane + 64] = o1;
}

// ---------------------------------------------------------------------------
// 256x256 tile, BK=64, 8 waves (2M x 4N), 8-phase pipelined schedule (T3+T4+T5).
// LDS 128 KiB = 2 K-tile buffers x {A: 2 halves x 128x64, B: same} bf16.
// Per phase: ds_read one quadrant's new frags | stage 1 half-tile (2 gload_lds)
//            | s_barrier | setprio(1) 16 MFMA setprio(0) | s_barrier.
// Quadrant rotation Q00->Q01->Q11->Q10 with full frag reuse:
//   q0 reads afA(8)+bfA(4), q1 bfB(4), q2 afB(8), q3 none (uses held afB,bfA).
// LDS half last-read: A-half at q2, B-half at q1.
// Stage stream order per tile: [B0,A0,A1,B1]; stream leads phases by 6 halves:
//   phase p stages stream idx 6+p; B0 of tile t issues at phase 4t-6 (q2 of
//   t-2, after its B-half q1 last-read barrier) -> no overwrite race.
// Boundary wait (end of q3): issued=4T+10 halves, need tile T+1 (<=4T+7) done
//   -> 2 halves may remain in flight -> s_waitcnt vmcnt(4). Last boundary
//   (T=6) has all 32 issued -> vmcnt(0). Never any other vmcnt drain.
// LDS chunk swizzle: 16B chunk c of row r lives at slot c^(r&7);
// global_load_lds dest is linear so the GLOBAL chunk is permuted instead.
// ---------------------------------------------------------------------------
#define BAR()    __builtin_amdgcn_s_barrier()
#define WAITV4() asm volatile("s_waitcnt vmcnt(4)" ::: "memory")
#define WAITV0() asm volatile("s_waitcnt vmcnt(0)" ::: "memory")

__global__ __launch_bounds__(512, 2) void gemm_fused_kernel(
    const unsigned short* __restrict__ an, const unsigned short* __restrict__ bn,
    const int* __restrict__ labels, float* __restrict__ cos_out,
    float* __restrict__ num, float* __restrict__ den)
{
    __shared__ __align__(16) char lds[131072];
    char* ldsC = (char*)lds;

    const int t = threadIdx.x;
    const int wid = t >> 6;        // 0..7
    const int lane = t & 63;
    const int quad = lane >> 4;
    const int lr = lane & 15;
    const int sx = lr & 7;         // row&7 for all fragment rows (rows = 16*frag + lr)
    const int bm = blockIdx.y;     // 32 M-blocks
    const int bnb = blockIdx.x;    // 32 N-blocks
    const int wm = wid >> 2;       // 0..1  -> rows wm*128..+127
    const int wn = wid & 3;        // 0..3  -> cols wn*64..+63

    f32x4 acc[8][4] = {};

    // --- staging address precompute (2 gload_lds per thread per half-tile) ---
    // thread t, piece j: LDS chunks li = (j*8+wid)*64 + lane; slot li holds
    // global chunk (li&7)^(r&7) of half-row r = li>>3.
    unsigned rowOff[2], ldsW[2];
#pragma unroll
    for (int j = 0; j < 2; ++j) {
        int li = (j * 8 + wid) * 64 + lane;
        int r  = li >> 3;
        int gc = (li & 7) ^ (r & 7);
        rowOff[j] = (unsigned)(r * (DDIM * 2) + gc * 16);
        ldsW[j]   = (unsigned)((j * 8 + wid) * 1024);
    }
    const char* aT = (const char*)an + (size_t)(bm * 256) * (DDIM * 2);
    const char* bT = (const char*)bn + (size_t)(bnb * 256) * (DDIM * 2);

    // stage stream index i: tile=i>>2, role=i&3 in [B0,A0,A1,B1]
    auto STG = [&](int i) {
        const int tile = i >> 2, role = i & 3;
        const int isA = (role == 1 || role == 2);
        const int h   = (role == 2 || role == 3);
        const unsigned ldsBase = (unsigned)((tile & 1) * 65536) +
                                 (isA ? 0u : 32768u) + (unsigned)(h * 16384);
        const char* g = (isA ? aT : bT) + h * (128 * DDIM * 2) + tile * 128;
        __builtin_amdgcn_global_load_lds(
            (const __attribute__((address_space(1))) void*)(g + rowOff[0]),
            (__attribute__((address_space(3))) void*)(ldsC + ldsBase + ldsW[0]), 16, 0, 0);
        __builtin_amdgcn_global_load_lds(
            (const __attribute__((address_space(1))) void*)(g + rowOff[1]),
            (__attribute__((address_space(3))) void*)(ldsC + ldsBase + ldsW[1]), 16, 0, 0);
    };

    bf16x8 afA[4][2], afB[4][2], bfA[2][2], bfB[2][2];

    auto MMAQ = [&](int mh, int nh, bf16x8 (&afX)[4][2], bf16x8 (&bfX)[2][2]) {
        __builtin_amdgcn_s_setprio(1);
#pragma unroll
        for (int kk = 0; kk < 2; ++kk)
#pragma unroll
            for (int mi = 0; mi < 4; ++mi)
#pragma unroll
                for (int ni = 0; ni < 2; ++ni)
                    acc[mh * 4 + mi][nh * 2 + ni] =
                        __builtin_amdgcn_mfma_f32_16x16x32_bf16(
                            afX[mi][kk], bfX[ni][kk],
                            acc[mh * 4 + mi][nh * 2 + ni], 0, 0, 0);
        __builtin_amdgcn_s_setprio(0);
    };

    // --- prologue: tile0 complete + 2 halves of tile1 in flight ---
    STG(0); STG(1); STG(2); STG(3); STG(4); STG(5);
    WAITV4();   // oldest 8 loads (tile0's 4 halves) complete
    BAR();

#pragma unroll
    for (int T = 0; T < 8; ++T) {
        const unsigned bufO  = (unsigned)((T & 1) * 65536);
        const unsigned aBase = bufO + (unsigned)(wm * 16384);
        const unsigned bBase = bufO + 32768u + (unsigned)((wn >> 1) * 16384);
        const int brp = (wn & 1) * 64;

        // ---- q0: read afA (mi 0-3) + bfA (ni 0-1); Q(0,0) ----
#pragma unroll
        for (int mi = 0; mi < 4; ++mi)
#pragma unroll
            for (int kk = 0; kk < 2; ++kk) {
                int rp = mi * 16 + lr;
                afA[mi][kk] = *(const bf16x8*)(ldsC + aBase + rp * 128 +
                                               (((kk * 4 + quad) ^ sx) << 4));
            }
#pragma unroll
        for (int ni = 0; ni < 2; ++ni)
#pragma unroll
            for (int kk = 0; kk < 2; ++kk) {
                int rp = brp + ni * 16 + lr;
                bfA[ni][kk] = *(const bf16x8*)(ldsC + bBase + rp * 128 +
                                               (((kk * 4 + quad) ^ sx) << 4));
            }
        if (6 + 4 * T < 32) STG(6 + 4 * T);
        BAR();
        MMAQ(0, 0, afA, bfA);
        BAR();

        // ---- q1: read bfB (ni 2-3); Q(0,1) ----
#pragma unroll
        for (int ni = 0; ni < 2; ++ni)
#pragma unroll
            for (int kk = 0; kk < 2; ++kk) {
                int rp = brp + (ni + 2) * 16 + lr;
                bfB[ni][kk] = *(const bf16x8*)(ldsC + bBase + rp * 128 +
                                               (((kk * 4 + quad) ^ sx) << 4));
            }
        if (7 + 4 * T < 32) STG(7 + 4 * T);
        BAR();
        MMAQ(0, 1, afA, bfB);
        BAR();

        // ---- q2: read afB (mi 4-7); Q(1,1) ----
#pragma unroll
        for (int mi = 0; mi < 4; ++mi)
#pragma unroll
            for (int kk = 0; kk < 2; ++kk) {
                int rp = (mi + 4) * 16 + lr;
                afB[mi][kk] = *(const bf16x8*)(ldsC + aBase + rp * 128 +
                                               (((kk * 4 + quad) ^ sx) << 4));
            }
        if (8 + 4 * T < 32) STG(8 + 4 * T);
        BAR();
        MMAQ(1, 1, afB, bfB);
        BAR();

        // ---- q3: no reads (held afB, bfA); Q(1,0); K-tile boundary wait ----
        if (9 + 4 * T < 32) STG(9 + 4 * T);
        BAR();
        MMAQ(1, 0, afB, bfA);
        if (T < 6) { WAITV4(); BAR(); }
        else if (T == 6) { WAITV0(); BAR(); }
        // T==7: fall through to epilogue, no LDS use follows
    }

    // --- Epilogue: nontemporal cos store + fused masked/unmasked exp sums ---
    // C/D layout (m89/m91): col = lane&15, row = quad*4 + reg.
    const float INV_T = 1.0f / 0.07f;
    const int col0 = bnb * 256 + wn * 64 + lr;
    int lab_c[4];
#pragma unroll
    for (int ni = 0; ni < 4; ++ni) lab_c[ni] = labels[col0 + ni * 16];

#pragma unroll
    for (int mi = 0; mi < 8; ++mi) {
        int rbase = bm * 256 + wm * 128 + mi * 16 + quad * 4;
#pragma unroll
        for (int r = 0; r < 4; ++r) {
            int row = rbase + r;
            int lab_r = labels[row];
            float dsum = 0.0f, nsum = 0.0f;
#pragma unroll
            for (int ni = 0; ni < 4; ++ni) {
                float cv = acc[mi][ni][r];
                __builtin_nontemporal_store(cv, &cos_out[(size_t)row * BDIM + col0 + ni * 16]);
                float e = __expf(cv * INV_T);
                dsum += e;
                nsum += (lab_c[ni] == lab_r) ? e : 0.0f;
            }
#pragma unroll
            for (int m = 1; m < 16; m <<= 1) {
                dsum += __shfl_xor(dsum, m);
                nsum += __shfl_xor(nsum, m);
            }
            if (lr == 0) {
                atomicAdd(&den[row], dsum);
                atomicAdd(&num[row], nsum);
            }
        }
    }
}

__global__ __launch_bounds__(1024) void loss_kernel(
    const float* __restrict__ num, const float* __restrict__ den,
    float* __restrict__ out)
{
    int t = threadIdx.x;
    float s = 0.0f;
#pragma unroll
    for (int i = 0; i < 8; ++i) {
        int idx = t + i * 1024;
        s += __logf(num[idx] / den[idx]);
    }
#pragma unroll
    for (int m = 1; m < 64; m <<= 1) s += __shfl_xor(s, m);
    __shared__ float red[16];
    if ((t & 63) == 0) red[t >> 6] = s;
    __syncthreads();
    if (t == 0) {
        float tot = 0.0f;
#pragma unroll
        for (int i = 0; i < 16; ++i) tot += red[i];
        out[0] = -tot / (float)BDIM;
    }
}

extern "C" void kernel_launch(void* const* d_in, const int* in_sizes, int n_in,
                              void* d_out, int out_size, void* d_ws, size_t ws_size,
                              hipStream_t stream)
{
    const int* labels = (const int*)d_in[0];
    const float* fa = (const float*)d_in[1];
    const float* fb = (const float*)d_in[2];
    float* out = (float*)d_out;

    // ws: a_n bf16 (8 MB) | b_n bf16 (8 MB) | num f32 (32 KB) | den f32 (32 KB)
    unsigned short* an = (unsigned short*)d_ws;
    unsigned short* bn = an + (size_t)BDIM * DDIM;
    float* num = (float*)(bn + (size_t)BDIM * DDIM);
    float* den = num + BDIM;

    hipMemsetAsync(num, 0, 2 * BDIM * sizeof(float), stream);  // ws is poisoned each call
    normalize_kernel<<<4096, 256, 0, stream>>>(fa, fb, an, bn);
    dim3 grid(32, 32);
    gemm_fused_kernel<<<grid, 512, 0, stream>>>(an, bn, labels, out + 1, num, den);
    loss_kernel<<<1, 1024, 0, stream>>>(num, den, out);
}

// Round 3
// 390.871 us; speedup vs baseline: 1.0680x; 1.0680x over previous
//
#include <hip/hip_runtime.h>
#include <cstdint>
#include <cstddef>

#define BDIM 8192
#define DDIM 512

typedef __bf16 bf16x8 __attribute__((ext_vector_type(8)));
typedef float f32x4 __attribute__((ext_vector_type(4)));

__device__ inline unsigned short f32_to_bf16(float f) {
    unsigned int u = __float_as_uint(f);
    u += 0x7FFF + ((u >> 16) & 1);   // RNE
    return (unsigned short)(u >> 16);
}

// One WAVE per row (no LDS, no barriers). 256 threads = 4 rows/block.
__global__ __launch_bounds__(256) void normalize_kernel(
    const float* __restrict__ a, const float* __restrict__ b,
    unsigned short* __restrict__ an, unsigned short* __restrict__ bn)
{
    const int lane = threadIdx.x & 63;
    const int row = blockIdx.x * 4 + (threadIdx.x >> 6);
    const float* src;
    unsigned short* dst;
    if (row < BDIM) {
        src = a + (size_t)row * DDIM;
        dst = an + (size_t)row * DDIM;
    } else {
        src = b + (size_t)(row - BDIM) * DDIM;
        dst = bn + (size_t)(row - BDIM) * DDIM;
    }
    const float4* s4 = (const float4*)src;
    float4 v0 = s4[lane];
    float4 v1 = s4[lane + 64];
    float ss = v0.x * v0.x + v0.y * v0.y + v0.z * v0.z + v0.w * v0.w
             + v1.x * v1.x + v1.y * v1.y + v1.z * v1.z + v1.w * v1.w;
#pragma unroll
    for (int m = 1; m < 64; m <<= 1) ss += __shfl_xor(ss, m);
    float inv = 1.0f / fmaxf(sqrtf(ss), 1e-8f);
    ushort4 o0, o1;
    o0.x = f32_to_bf16(v0.x * inv); o0.y = f32_to_bf16(v0.y * inv);
    o0.z = f32_to_bf16(v0.z * inv); o0.w = f32_to_bf16(v0.w * inv);
    o1.x = f32_to_bf16(v1.x * inv); o1.y = f32_to_bf16(v1.y * inv);
    o1.z = f32_to_bf16(v1.z * inv); o1.w = f32_to_bf16(v1.w * inv);
    ushort4* d4 = (ushort4*)dst;
    d4[lane] = o0;
    d4[lane + 64] = o1;
}

// ---------------------------------------------------------------------------
// Main loop: unchanged 8-phase pipelined 256x256/BK=64 schedule (verified R2:
// 0 bank conflicts, counted vmcnt works). R2 post-mortem: limiter is the
// EPILOGUE store path (128 scalar dword stores/thread > 63-outstanding vmem
// cap -> waves block on HBM store latency with 1 blk/CU and nothing to
// overlap). New epilogue:
//  - per-wave LDS transpose patch (wid*4KB, region 0..32KB == buf0, quiescent:
//    T=6 boundary vmcnt(0)+barrier landed ALL gload_lds; T=7 waves read only
//    buf1 at 64..128KB) -> 32 nontemporal global_store_dwordx4 per thread
//    (full 256B segments, fits under the outstanding-store cap -> fire&forget).
//  - num/den: LDS partials part[wn][256][2] at 32KB, one __syncthreads, 512
//    atomics/block (was 2048) -> less L2 atomic churn (-~50MB WRITE_SIZE).
// ---------------------------------------------------------------------------
#define BAR()    __builtin_amdgcn_s_barrier()
#define WAITV4() asm volatile("s_waitcnt vmcnt(4)" ::: "memory")
#define WAITV0() asm volatile("s_waitcnt vmcnt(0)" ::: "memory")

__global__ __launch_bounds__(512, 2) void gemm_fused_kernel(
    const unsigned short* __restrict__ an, const unsigned short* __restrict__ bn,
    const int* __restrict__ labels, float* __restrict__ cos_out,
    float* __restrict__ num, float* __restrict__ den)
{
    __shared__ __align__(16) char lds[131072];
    char* ldsC = (char*)lds;

    const int t = threadIdx.x;
    const int wid = t >> 6;        // 0..7
    const int lane = t & 63;
    const int quad = lane >> 4;
    const int lr = lane & 15;
    const int sx = lr & 7;         // row&7 for all fragment rows (rows = 16*frag + lr)
    const int bm = blockIdx.y;     // 32 M-blocks
    const int bnb = blockIdx.x;    // 32 N-blocks
    const int wm = wid >> 2;       // 0..1  -> rows wm*128..+127
    const int wn = wid & 3;        // 0..3  -> cols wn*64..+63

    f32x4 acc[8][4] = {};

    // --- staging address precompute (2 gload_lds per thread per half-tile) ---
    unsigned rowOff[2], ldsW[2];
#pragma unroll
    for (int j = 0; j < 2; ++j) {
        int li = (j * 8 + wid) * 64 + lane;
        int r  = li >> 3;
        int gc = (li & 7) ^ (r & 7);
        rowOff[j] = (unsigned)(r * (DDIM * 2) + gc * 16);
        ldsW[j]   = (unsigned)((j * 8 + wid) * 1024);
    }
    const char* aT = (const char*)an + (size_t)(bm * 256) * (DDIM * 2);
    const char* bT = (const char*)bn + (size_t)(bnb * 256) * (DDIM * 2);

    // stage stream index i: tile=i>>2, role=i&3 in [B0,A0,A1,B1]
    auto STG = [&](int i) {
        const int tile = i >> 2, role = i & 3;
        const int isA = (role == 1 || role == 2);
        const int h   = (role == 2 || role == 3);
        const unsigned ldsBase = (unsigned)((tile & 1) * 65536) +
                                 (isA ? 0u : 32768u) + (unsigned)(h * 16384);
        const char* g = (isA ? aT : bT) + h * (128 * DDIM * 2) + tile * 128;
        __builtin_amdgcn_global_load_lds(
            (const __attribute__((address_space(1))) void*)(g + rowOff[0]),
            (__attribute__((address_space(3))) void*)(ldsC + ldsBase + ldsW[0]), 16, 0, 0);
        __builtin_amdgcn_global_load_lds(
            (const __attribute__((address_space(1))) void*)(g + rowOff[1]),
            (__attribute__((address_space(3))) void*)(ldsC + ldsBase + ldsW[1]), 16, 0, 0);
    };

    bf16x8 afA[4][2], afB[4][2], bfA[2][2], bfB[2][2];

    auto MMAQ = [&](int mh, int nh, bf16x8 (&afX)[4][2], bf16x8 (&bfX)[2][2]) {
        __builtin_amdgcn_s_setprio(1);
#pragma unroll
        for (int kk = 0; kk < 2; ++kk)
#pragma unroll
            for (int mi = 0; mi < 4; ++mi)
#pragma unroll
                for (int ni = 0; ni < 2; ++ni)
                    acc[mh * 4 + mi][nh * 2 + ni] =
                        __builtin_amdgcn_mfma_f32_16x16x32_bf16(
                            afX[mi][kk], bfX[ni][kk],
                            acc[mh * 4 + mi][nh * 2 + ni], 0, 0, 0);
        __builtin_amdgcn_s_setprio(0);
    };

    // --- prologue: tile0 complete + 2 halves of tile1 in flight ---
    STG(0); STG(1); STG(2); STG(3); STG(4); STG(5);
    WAITV4();
    BAR();

#pragma unroll
    for (int T = 0; T < 8; ++T) {
        const unsigned bufO  = (unsigned)((T & 1) * 65536);
        const unsigned aBase = bufO + (unsigned)(wm * 16384);
        const unsigned bBase = bufO + 32768u + (unsigned)((wn >> 1) * 16384);
        const int brp = (wn & 1) * 64;

        // ---- q0: read afA (mi 0-3) + bfA (ni 0-1); Q(0,0) ----
#pragma unroll
        for (int mi = 0; mi < 4; ++mi)
#pragma unroll
            for (int kk = 0; kk < 2; ++kk) {
                int rp = mi * 16 + lr;
                afA[mi][kk] = *(const bf16x8*)(ldsC + aBase + rp * 128 +
                                               (((kk * 4 + quad) ^ sx) << 4));
            }
#pragma unroll
        for (int ni = 0; ni < 2; ++ni)
#pragma unroll
            for (int kk = 0; kk < 2; ++kk) {
                int rp = brp + ni * 16 + lr;
                bfA[ni][kk] = *(const bf16x8*)(ldsC + bBase + rp * 128 +
                                               (((kk * 4 + quad) ^ sx) << 4));
            }
        if (6 + 4 * T < 32) STG(6 + 4 * T);
        BAR();
        MMAQ(0, 0, afA, bfA);
        BAR();

        // ---- q1: read bfB (ni 2-3); Q(0,1) ----
#pragma unroll
        for (int ni = 0; ni < 2; ++ni)
#pragma unroll
            for (int kk = 0; kk < 2; ++kk) {
                int rp = brp + (ni + 2) * 16 + lr;
                bfB[ni][kk] = *(const bf16x8*)(ldsC + bBase + rp * 128 +
                                               (((kk * 4 + quad) ^ sx) << 4));
            }
        if (7 + 4 * T < 32) STG(7 + 4 * T);
        BAR();
        MMAQ(0, 1, afA, bfB);
        BAR();

        // ---- q2: read afB (mi 4-7); Q(1,1) ----
#pragma unroll
        for (int mi = 0; mi < 4; ++mi)
#pragma unroll
            for (int kk = 0; kk < 2; ++kk) {
                int rp = (mi + 4) * 16 + lr;
                afB[mi][kk] = *(const bf16x8*)(ldsC + aBase + rp * 128 +
                                               (((kk * 4 + quad) ^ sx) << 4));
            }
        if (8 + 4 * T < 32) STG(8 + 4 * T);
        BAR();
        MMAQ(1, 1, afB, bfB);
        BAR();

        // ---- q3: no reads (held afB, bfA); Q(1,0); K-tile boundary wait ----
        if (9 + 4 * T < 32) STG(9 + 4 * T);
        BAR();
        MMAQ(1, 0, afB, bfA);
        if (T < 6) { WAITV4(); BAR(); }
        else if (T == 6) { WAITV0(); BAR(); }
        // T==7: fall through to epilogue (no LDS buffer use after this)
    }

    // --- Epilogue v2: LDS-transposed coalesced stores + LDS-reduced atomics ---
    // C/D layout (m89/m91): col = lane&15, row = quad*4 + reg.
    const float INV_T = 1.0f / 0.07f;
    const int col0 = bnb * 256 + wn * 64 + lr;
    int lab_c[4];
#pragma unroll
    for (int ni = 0; ni < 4; ++ni) lab_c[ni] = labels[col0 + ni * 16];

    float* patch = (float*)(ldsC + wid * 4096);   // wave-private 16x64 f32
    float* part  = (float*)(ldsC + 32768);        // [wn][256][2] f32 partials

#pragma unroll
    for (int mi = 0; mi < 8; ++mi) {
        // 1) scatter acc fragment into wave-private patch (MFMA layout)
#pragma unroll
        for (int ni = 0; ni < 4; ++ni)
#pragma unroll
            for (int r = 0; r < 4; ++r)
                patch[(quad * 4 + r) * 64 + ni * 16 + lr] = acc[mi][ni][r];

        // 2) fused exp row-sums -> LDS partials (one slot per (wn,row))
#pragma unroll
        for (int r = 0; r < 4; ++r) {
            int rowL = wm * 128 + mi * 16 + quad * 4 + r;
            int lab_r = labels[bm * 256 + rowL];
            float dsum = 0.0f, nsum = 0.0f;
#pragma unroll
            for (int ni = 0; ni < 4; ++ni) {
                float e = __expf(acc[mi][ni][r] * INV_T);
                dsum += e;
                nsum += (lab_c[ni] == lab_r) ? e : 0.0f;
            }
#pragma unroll
            for (int m = 1; m < 16; m <<= 1) {
                dsum += __shfl_xor(dsum, m);
                nsum += __shfl_xor(nsum, m);
            }
            if (lr == 0) {
                float2 pv; pv.x = nsum; pv.y = dsum;
                *(float2*)&part[(size_t)(wn * 256 + rowL) * 2] = pv;
            }
        }

        // 3) coalesced nontemporal float4 stores (4 rows x 256B per instr)
#pragma unroll
        for (int p = 0; p < 4; ++p) {
            f32x4 v = *(const f32x4*)&patch[(p * 4 + quad) * 64 + lr * 4];
            int row = bm * 256 + wm * 128 + mi * 16 + p * 4 + quad;
            f32x4* gp = (f32x4*)&cos_out[(size_t)row * BDIM + bnb * 256 + wn * 64 + lr * 4];
            __builtin_nontemporal_store(v, gp);
        }
    }

    __syncthreads();
    if (t < 256) {
        float2 p0 = *(float2*)&part[(size_t)(0 * 256 + t) * 2];
        float2 p1 = *(float2*)&part[(size_t)(1 * 256 + t) * 2];
        float2 p2 = *(float2*)&part[(size_t)(2 * 256 + t) * 2];
        float2 p3 = *(float2*)&part[(size_t)(3 * 256 + t) * 2];
        int row = bm * 256 + t;
        atomicAdd(&num[row], p0.x + p1.x + p2.x + p3.x);
        atomicAdd(&den[row], p0.y + p1.y + p2.y + p3.y);
    }
}

__global__ __launch_bounds__(1024) void loss_kernel(
    const float* __restrict__ num, const float* __restrict__ den,
    float* __restrict__ out)
{
    int t = threadIdx.x;
    float s = 0.0f;
#pragma unroll
    for (int i = 0; i < 8; ++i) {
        int idx = t + i * 1024;
        s += __logf(num[idx] / den[idx]);
    }
#pragma unroll
    for (int m = 1; m < 64; m <<= 1) s += __shfl_xor(s, m);
    __shared__ float red[16];
    if ((t & 63) == 0) red[t >> 6] = s;
    __syncthreads();
    if (t == 0) {
        float tot = 0.0f;
#pragma unroll
        for (int i = 0; i < 16; ++i) tot += red[i];
        out[0] = -tot / (float)BDIM;
    }
}

extern "C" void kernel_launch(void* const* d_in, const int* in_sizes, int n_in,
                              void* d_out, int out_size, void* d_ws, size_t ws_size,
                              hipStream_t stream)
{
    const int* labels = (const int*)d_in[0];
    const float* fa = (const float*)d_in[1];
    const float* fb = (const float*)d_in[2];
    float* out = (float*)d_out;

    // ws: a_n bf16 (8 MB) | b_n bf16 (8 MB) | num f32 (32 KB) | den f32 (32 KB)
    unsigned short* an = (unsigned short*)d_ws;
    unsigned short* bn = an + (size_t)BDIM * DDIM;
    float* num = (float*)(bn + (size_t)BDIM * DDIM);
    float* den = num + BDIM;

    hipMemsetAsync(num, 0, 2 * BDIM * sizeof(float), stream);  // ws is poisoned each call
    normalize_kernel<<<4096, 256, 0, stream>>>(fa, fb, an, bn);
    dim3 grid(32, 32);
    gemm_fused_kernel<<<grid, 512, 0, stream>>>(an, bn, labels, out + 1, num, den);
    loss_kernel<<<1, 1024, 0, stream>>>(num, den, out);
}

// Round 4
// 369.802 us; speedup vs baseline: 1.1289x; 1.0570x over previous
//
#include <hip/hip_runtime.h>
#include <cstdint>
#include <cstddef>

#define BDIM 8192
#define DDIM 512

typedef __bf16 bf16x8 __attribute__((ext_vector_type(8)));
typedef float f32x4 __attribute__((ext_vector_type(4)));

__device__ inline unsigned short f32_to_bf16(float f) {
    unsigned int u = __float_as_uint(f);
    u += 0x7FFF + ((u >> 16) & 1);   // RNE
    return (unsigned short)(u >> 16);
}

// One WAVE per row (no LDS, no barriers). 256 threads = 4 rows/block.
__global__ __launch_bounds__(256) void normalize_kernel(
    const float* __restrict__ a, const float* __restrict__ b,
    unsigned short* __restrict__ an, unsigned short* __restrict__ bn)
{
    const int lane = threadIdx.x & 63;
    const int row = blockIdx.x * 4 + (threadIdx.x >> 6);
    const float* src;
    unsigned short* dst;
    if (row < BDIM) {
        src = a + (size_t)row * DDIM;
        dst = an + (size_t)row * DDIM;
    } else {
        src = b + (size_t)(row - BDIM) * DDIM;
        dst = bn + (size_t)(row - BDIM) * DDIM;
    }
    const float4* s4 = (const float4*)src;
    float4 v0 = s4[lane];
    float4 v1 = s4[lane + 64];
    float ss = v0.x * v0.x + v0.y * v0.y + v0.z * v0.z + v0.w * v0.w
             + v1.x * v1.x + v1.y * v1.y + v1.z * v1.z + v1.w * v1.w;
#pragma unroll
    for (int m = 1; m < 64; m <<= 1) ss += __shfl_xor(ss, m);
    float inv = 1.0f / fmaxf(sqrtf(ss), 1e-8f);
    ushort4 o0, o1;
    o0.x = f32_to_bf16(v0.x * inv); o0.y = f32_to_bf16(v0.y * inv);
    o0.z = f32_to_bf16(v0.z * inv); o0.w = f32_to_bf16(v0.w * inv);
    o1.x = f32_to_bf16(v1.x * inv); o1.y = f32_to_bf16(v1.y * inv);
    o1.z = f32_to_bf16(v1.z * inv); o1.w = f32_to_bf16(v1.w * inv);
    ushort4* d4 = (ushort4*)dst;
    d4[lane] = o0;
    d4[lane + 64] = o1;
}

// ---------------------------------------------------------------------------
// R3 post-mortem: both prior structures ran exactly 2 waves/SIMD (R0: VGPR-
// capped; R2/R3: 128KiB LDS -> 1 blk/CU) and both sat ~160us with NOTHING
// saturated (Mfma 15 / VALU 16 / HBM 27 / Occ 21) => latency-bound, and at
// K=512 (32 phases) per-block fill/drain is exposed 4 serial times.
// Fix = TLP: 128x128 tile, BK=64, 4 waves, 32KiB single-buffer LDS, plain
// 2-phase m97 structure (912 TF verified at this tile, ~3 blk/CU), acc[4][4]
// (64 VGPR) + __launch_bounds__(256,3) -> ~3 blocks/CU = 12 waves/CU; 4096
// blocks over ~5 rounds so fills/drains/stores of different blocks overlap.
// LDS chunk swizzle kept: 16B chunk c of row r lives at slot c^(r&7);
// global_load_lds dest is linear so the GLOBAL chunk index is permuted.
// Epilogue: per-wave LDS transpose patch (row stride 272B = 17*16B: 16B-
// aligned, quad-row bank shift 16 -> no 4-way write conflict) then 16
// nontemporal global_store_dwordx4/thread; num/den via LDS partials ->
// 256 atomics/block.
// ---------------------------------------------------------------------------
__global__ __launch_bounds__(256, 3) void gemm_fused_kernel(
    const unsigned short* __restrict__ an, const unsigned short* __restrict__ bn,
    const int* __restrict__ labels, float* __restrict__ cos_out,
    float* __restrict__ num, float* __restrict__ den)
{
    __shared__ __align__(16) char lds[32768];
    char* ldsC = (char*)lds;
    char* sA = ldsC;            // 128x64 bf16 = 16 KiB
    char* sB = ldsC + 16384;    // 128x64 bf16 = 16 KiB

    const int t = threadIdx.x;
    const int wid = t >> 6;        // 0..3
    const int lane = t & 63;
    const int quad = lane >> 4;
    const int lr = lane & 15;
    const int bm = blockIdx.y;     // 64 M-blocks
    const int bnb = blockIdx.x;    // 64 N-blocks
    const int wm = wid >> 1;       // rows wm*64..+63
    const int wn = wid & 1;        // cols wn*64..+63

    f32x4 acc[4][4] = {};

    // staging: thread t, call c moves 16B to LDS chunk li = c*256+t; that slot
    // holds global chunk (li&7)^(r&7) of tile row r = li>>3.
    unsigned gOffA[4], gOffB[4];
#pragma unroll
    for (int c = 0; c < 4; ++c) {
        int li = c * 256 + t;
        int r = li >> 3;
        int cch = (li & 7) ^ (r & 7);
        gOffA[c] = (unsigned)((bm * 128 + r) * (DDIM * 2) + cch * 16);
        gOffB[c] = (unsigned)((bnb * 128 + r) * (DDIM * 2) + cch * 16);
    }
    const char* aBase = (const char*)an;
    const char* bBase = (const char*)bn;

    for (int k0 = 0; k0 < DDIM; k0 += 64) {
#pragma unroll
        for (int c = 0; c < 4; ++c)
            __builtin_amdgcn_global_load_lds(
                (const __attribute__((address_space(1))) void*)(aBase + gOffA[c] + k0 * 2),
                (__attribute__((address_space(3))) void*)(sA + c * 4096 + t * 16),
                16, 0, 0);
#pragma unroll
        for (int c = 0; c < 4; ++c)
            __builtin_amdgcn_global_load_lds(
                (const __attribute__((address_space(1))) void*)(bBase + gOffB[c] + k0 * 2),
                (__attribute__((address_space(3))) void*)(sB + c * 4096 + t * 16),
                16, 0, 0);
        __syncthreads();   // compiler drains vmcnt before barrier (single-buffer needs it)

        bf16x8 af[4][2], bf[4][2];
#pragma unroll
        for (int mi = 0; mi < 4; ++mi)
#pragma unroll
            for (int kk = 0; kk < 2; ++kk) {
                int rp = wm * 64 + mi * 16 + lr;
                af[mi][kk] = *(const bf16x8*)(sA + rp * 128 +
                                              (((kk * 4 + quad) ^ (rp & 7)) << 4));
            }
#pragma unroll
        for (int ni = 0; ni < 4; ++ni)
#pragma unroll
            for (int kk = 0; kk < 2; ++kk) {
                int rp = wn * 64 + ni * 16 + lr;
                bf[ni][kk] = *(const bf16x8*)(sB + rp * 128 +
                                              (((kk * 4 + quad) ^ (rp & 7)) << 4));
            }
#pragma unroll
        for (int kk = 0; kk < 2; ++kk)
#pragma unroll
            for (int mi = 0; mi < 4; ++mi)
#pragma unroll
                for (int ni = 0; ni < 4; ++ni)
                    acc[mi][ni] = __builtin_amdgcn_mfma_f32_16x16x32_bf16(
                        af[mi][kk], bf[ni][kk], acc[mi][ni], 0, 0, 0);
        __syncthreads();   // reads done before next stage overwrites
    }

    // --- Epilogue: LDS-transposed coalesced stores + LDS-reduced atomics ---
    // C/D layout (m89/m91): col = lane&15, row = quad*4 + reg.
    const float INV_T = 1.0f / 0.07f;
    const int col0 = bnb * 128 + wn * 64 + lr;
    int lab_c[4];
#pragma unroll
    for (int ni = 0; ni < 4; ++ni) lab_c[ni] = labels[col0 + ni * 16];

    // wave-private 16x64 f32 patch, row stride 68 f32 (272 B): 16B-aligned,
    // quad-row bank offset 16 -> conflict-light scatter and b128 gather.
    float* patch = (float*)(ldsC + wid * 4352);
    float* part  = (float*)(ldsC + 17408);   // [wn][128][2] f32 partials

#pragma unroll
    for (int mi = 0; mi < 4; ++mi) {
        // 1) scatter acc fragment into patch (MFMA layout -> row-major)
#pragma unroll
        for (int ni = 0; ni < 4; ++ni)
#pragma unroll
            for (int r = 0; r < 4; ++r)
                patch[(quad * 4 + r) * 68 + ni * 16 + lr] = acc[mi][ni][r];

        // 2) fused exp row-sums -> LDS partials
#pragma unroll
        for (int r = 0; r < 4; ++r) {
            int rowL = wm * 64 + mi * 16 + quad * 4 + r;
            int lab_r = labels[bm * 128 + rowL];
            float dsum = 0.0f, nsum = 0.0f;
#pragma unroll
            for (int ni = 0; ni < 4; ++ni) {
                float e = __expf(acc[mi][ni][r] * INV_T);
                dsum += e;
                nsum += (lab_c[ni] == lab_r) ? e : 0.0f;
            }
#pragma unroll
            for (int m = 1; m < 16; m <<= 1) {
                dsum += __shfl_xor(dsum, m);
                nsum += __shfl_xor(nsum, m);
            }
            if (lr == 0) {
                float2 pv; pv.x = nsum; pv.y = dsum;
                *(float2*)&part[(size_t)(wn * 128 + rowL) * 2] = pv;
            }
        }

        // 3) coalesced nontemporal dwordx4 stores (4 rows x 256B per instr)
#pragma unroll
        for (int p = 0; p < 4; ++p) {
            f32x4 v = *(const f32x4*)&patch[(p * 4 + quad) * 68 + lr * 4];
            int row = bm * 128 + wm * 64 + mi * 16 + p * 4 + quad;
            f32x4* gp = (f32x4*)&cos_out[(size_t)row * BDIM + bnb * 128 + wn * 64 + lr * 4];
            __builtin_nontemporal_store(v, gp);
        }
    }

    __syncthreads();
    if (t < 128) {
        float2 p0 = *(float2*)&part[(size_t)(0 * 128 + t) * 2];
        float2 p1 = *(float2*)&part[(size_t)(1 * 128 + t) * 2];
        int row = bm * 128 + t;
        atomicAdd(&num[row], p0.x + p1.x);
        atomicAdd(&den[row], p0.y + p1.y);
    }
}

__global__ __launch_bounds__(1024) void loss_kernel(
    const float* __restrict__ num, const float* __restrict__ den,
    float* __restrict__ out)
{
    int t = threadIdx.x;
    float s = 0.0f;
#pragma unroll
    for (int i = 0; i < 8; ++i) {
        int idx = t + i * 1024;
        s += __logf(num[idx] / den[idx]);
    }
#pragma unroll
    for (int m = 1; m < 64; m <<= 1) s += __shfl_xor(s, m);
    __shared__ float red[16];
    if ((t & 63) == 0) red[t >> 6] = s;
    __syncthreads();
    if (t == 0) {
        float tot = 0.0f;
#pragma unroll
        for (int i = 0; i < 16; ++i) tot += red[i];
        out[0] = -tot / (float)BDIM;
    }
}

extern "C" void kernel_launch(void* const* d_in, const int* in_sizes, int n_in,
                              void* d_out, int out_size, void* d_ws, size_t ws_size,
                              hipStream_t stream)
{
    const int* labels = (const int*)d_in[0];
    const float* fa = (const float*)d_in[1];
    const float* fb = (const float*)d_in[2];
    float* out = (float*)d_out;

    // ws: a_n bf16 (8 MB) | b_n bf16 (8 MB) | num f32 (32 KB) | den f32 (32 KB)
    unsigned short* an = (unsigned short*)d_ws;
    unsigned short* bn = an + (size_t)BDIM * DDIM;
    float* num = (float*)(bn + (size_t)BDIM * DDIM);
    float* den = num + BDIM;

    hipMemsetAsync(num, 0, 2 * BDIM * sizeof(float), stream);  // ws is poisoned each call
    normalize_kernel<<<4096, 256, 0, stream>>>(fa, fb, an, bn);
    dim3 grid(64, 64);
    gemm_fused_kernel<<<grid, 256, 0, stream>>>(an, bn, labels, out + 1, num, den);
    loss_kernel<<<1, 1024, 0, stream>>>(num, den, out);
}